// Round 4
// baseline (112.925 us; speedup 1.0000x reference)
//
#include <hip/hip_runtime.h>
#include <hip/hip_bf16.h>
#include <math.h>
#include <stdint.h>

#define DM 4096
#define NEXP 64
#define BK 64            // k per chunk
#define NCH (DM / BK)    // 64 chunks
#define TOKPB 32         // tokens per block

typedef short bf16x8 __attribute__((ext_vector_type(8)));
typedef float f32x4  __attribute__((ext_vector_type(4)));

// LDS: X planes [buf][plane][32 tok][8 granules*16B] = 2*2*32*128 = 16384 B.
// Logits (32 x 66 f32 = 8448 B) overlay the X region after the K-loop.
#define SMEM_BYTES 16384

// RN split: x = hi + lo + f, |f| <= 2^-18 |x|. lo = x - hi is Sterbenz-exact.
__device__ __forceinline__ void split2(float f0, float f1, uint32_t& hw, uint32_t& lw) {
    float2 ff; ff.x = f0; ff.y = f1;
    __hip_bfloat162 h = __float22bfloat162_rn(ff);
    union { __hip_bfloat162 b; uint32_t u; } ch; ch.b = h;
    hw = ch.u;
    float h0 = __bfloat162float(h.x);
    float h1 = __bfloat162float(h.y);
    float2 gg; gg.x = f0 - h0; gg.y = f1 - h1;
    __hip_bfloat162 l = __float22bfloat162_rn(gg);
    union { __hip_bfloat162 b; uint32_t u; } cl; cl.b = l;
    lw = cl.u;
}

// ---------------- pre-pass: W fp32 -> RN bf16 hi/lo, fragment-ordered blob ----------------
// blob byte layout: c*16384 + ks*4096 + n4*1024 + lane*16 (hi; +8192 for lo)
// where lane = (e&15) | ((kgran&3)<<4), n4 = e>>4, ks = kgran>>2.
__global__ __launch_bounds__(512) void wsplit_kernel(const float* __restrict__ W,
                                                     char* __restrict__ blob) {
    const int c   = blockIdx.x;        // 0..63
    const int tid = threadIdx.x;       // 0..511
    const int e   = tid >> 3;          // expert 0..63
    const int g   = tid & 7;           // k-granule 0..7 (8 bf16 each)

    const float* src = W + (size_t)e * DM + c * BK + g * 8;
    float x[8];
    *(float4*)(x)     = *(const float4*)(src);
    *(float4*)(x + 4) = *(const float4*)(src + 4);

    uint32_t hiw[4], low[4];
#pragma unroll
    for (int j = 0; j < 4; ++j) split2(x[2 * j], x[2 * j + 1], hiw[j], low[j]);

    const int ks = g >> 2;
    const int ln = (e & 15) | ((g & 3) << 4);
    const int n4 = e >> 4;
    const size_t base = (size_t)c * 16384 + (size_t)ks * 4096 + (size_t)n4 * 1024 + (size_t)ln * 16;
    *(uint4*)(blob + base)        = *(uint4*)hiw;   // hi plane
    *(uint4*)(blob + base + 8192) = *(uint4*)low;   // lo plane
}

// ---------------- main kernel ----------------
// 256 threads = 4 waves. Wave w computes 32 tokens x experts [16w, 16w+16).
__global__ __launch_bounds__(256) void router_mfma_kernel(
    const float* __restrict__ X,
    const char* __restrict__ blob,
    const float* __restrict__ Bv,
    float* __restrict__ out)
{
    __shared__ __align__(16) char smem[SMEM_BYTES];

    const int tid  = threadIdx.x;      // 0..255
    const int lane = tid & 63;
    const int wv   = tid >> 6;         // 0..3 (expert quad)
    const long tok0 = (long)blockIdx.x * TOKPB;

    // X staging mapping: thread -> (token, k-granule)
    const int tkn = tid >> 3;          // 0..31
    const int kq  = tid & 7;           // 0..7
    const size_t rowbase = (size_t)(tok0 + tkn) * DM + kq * 8;

    f32x4 acc[2];
    acc[0] = (f32x4)0.0f;
    acc[1] = (f32x4)0.0f;

    float xa[8], xb[8];

    auto loadX = [&](float* xr, int c) {
        const float* p = X + rowbase + c * BK;
        *(float4*)(xr)     = *(const float4*)(p);
        *(float4*)(xr + 4) = *(const float4*)(p + 4);
    };

    auto cvtWrite = [&](const float* xr, int buf) {
        uint32_t hw[4], lw[4];
#pragma unroll
        for (int j = 0; j < 4; ++j) split2(xr[2 * j], xr[2 * j + 1], hw[j], lw[j]);
        const int slot = (kq ^ (tkn & 7)) * 16;
        char* bh = smem + ((buf * 2 + 0) * TOKPB + tkn) * 128;
        char* bl = smem + ((buf * 2 + 1) * TOKPB + tkn) * 128;
        *(uint4*)(bh + slot) = *(uint4*)hw;
        *(uint4*)(bl + slot) = *(uint4*)lw;
    };

    const int tk = lane & 15;          // token within 16-tile
    const int kg = lane >> 4;          // k-granule within 32-k subtile
    const int sw = lane & 7;           // swizzle key (== tk & 7 for both m-tiles)

    auto compute = [&](int buf, int c) {
        const char* bb = blob + (size_t)c * 16384;
#pragma unroll
        for (int ks = 0; ks < 2; ++ks) {
            const int slot = ((ks * 4 + kg) ^ sw) * 16;
            const size_t bo = (size_t)ks * 4096 + (size_t)wv * 1024 + (size_t)lane * 16;
            bf16x8 bh = *(const bf16x8*)(bb + bo);
            bf16x8 bl = *(const bf16x8*)(bb + 8192 + bo);
#pragma unroll
            for (int m = 0; m < 2; ++m) {
                const int row = m * 16 + tk;
                bf16x8 ah = *(const bf16x8*)(smem + ((buf * 2 + 0) * TOKPB + row) * 128 + slot);
                bf16x8 al = *(const bf16x8*)(smem + ((buf * 2 + 1) * TOKPB + row) * 128 + slot);
                acc[m] = __builtin_amdgcn_mfma_f32_16x16x32_bf16(ah, bh, acc[m], 0, 0, 0);
                acc[m] = __builtin_amdgcn_mfma_f32_16x16x32_bf16(ah, bl, acc[m], 0, 0, 0);
                acc[m] = __builtin_amdgcn_mfma_f32_16x16x32_bf16(al, bh, acc[m], 0, 0, 0);
                acc[m] = __builtin_amdgcn_mfma_f32_16x16x32_bf16(al, bl, acc[m], 0, 0, 0);
            }
        }
    };

    // ---- prologue: 2-deep prefetch ----
    loadX(xa, 0);
    loadX(xb, 1);
    cvtWrite(xa, 0);
    __syncthreads();

    // ---- main loop: 2 chunks per iteration; loads issued 2 chunks ahead ----
#pragma unroll 1
    for (int cc = 0; cc < NCH / 2; ++cc) {
        const int c0 = 2 * cc;
        if (c0 + 2 < NCH) loadX(xa, c0 + 2);
        compute(0, c0);
        cvtWrite(xb, 1);
        __syncthreads();
        if (c0 + 3 < NCH) loadX(xb, c0 + 3);
        compute(1, c0 + 1);
        if (c0 + 2 < NCH) cvtWrite(xa, 0);
        __syncthreads();
    }

    // ---- logits to LDS (overlay X region): C row=(lane>>4)*4+r (token), col=lane&15 (expert) ----
#pragma unroll
    for (int m = 0; m < 2; ++m) {
        const int ee = wv * 16 + tk;
#pragma unroll
        for (int r = 0; r < 4; ++r) {
            const int tl = m * 16 + kg * 4 + r;
            *(float*)(smem + tl * 264 + ee * 4) = acc[m][r];
        }
    }
    __syncthreads();

    // ---- epilogue: bias + softmax + top-2 + dense scatter (lane = expert) ----
    const float bias = Bv[lane];
#pragma unroll 1
    for (int j = 0; j < 8; ++j) {
        const int t = wv * 8 + j;
        float v = *(const float*)(smem + t * 264 + lane * 4) + bias;

        float m1 = v;        int i1 = lane;
        float m2 = -3.4e38f; int i2 = 127;
#pragma unroll
        for (int s = 1; s < 64; s <<= 1) {
            float om1 = __shfl_xor(m1, s, 64);
            int   oi1 = __shfl_xor(i1, s, 64);
            float om2 = __shfl_xor(m2, s, 64);
            int   oi2 = __shfl_xor(i2, s, 64);
            bool bw = (om1 > m1) || (om1 == m1 && oi1 < i1);
            float l1v = bw ? m1 : om1;  int l1i = bw ? i1 : oi1;
            float w2v = bw ? om2 : m2;  int w2i = bw ? oi2 : i2;
            if (bw) { m1 = om1; i1 = oi1; }
            bool tw = (l1v > w2v) || (l1v == w2v && l1i < w2i);
            m2 = tw ? l1v : w2v;  i2 = tw ? l1i : w2i;
        }

        float p = expf(v - m1);
        float ssum = p;
#pragma unroll
        for (int s = 1; s < 64; s <<= 1) ssum += __shfl_xor(ssum, s, 64);

        float sc = (lane == i1 || lane == i2) ? (p / ssum) : 0.0f;
        out[(size_t)(tok0 + t) * NEXP + lane] = sc;
    }
}

extern "C" void kernel_launch(void* const* d_in, const int* in_sizes, int n_in,
                              void* d_out, int out_size, void* d_ws, size_t ws_size,
                              hipStream_t stream) {
    const float* X  = (const float*)d_in[0];   // [4,4096,4096] fp32
    const float* W  = (const float*)d_in[1];   // [64,4096] fp32
    const float* Bv = (const float*)d_in[2];   // [64] fp32
    float* out = (float*)d_out;                // [4,4096,64] fp32

    // W split blob: 64 chunks * 16 KiB = 1 MiB in d_ws
    char* blob = (char*)d_ws;
    wsplit_kernel<<<dim3(NCH), dim3(512), 0, stream>>>(W, blob);

    const int n_tokens = 4 * 4096;             // 16384
    router_mfma_kernel<<<dim3(n_tokens / TOKPB), dim3(256), 0, stream>>>(X, blob, Bv, out);
}

// Round 5
// 76.025 us; speedup vs baseline: 1.4854x; 1.4854x over previous
//
#include <hip/hip_runtime.h>
#include <hip/hip_bf16.h>
#include <math.h>
#include <stdint.h>

#define DM 4096
#define NEXP 64
#define BK 64              // k per chunk
#define NCH (DM / BK)      // 64 chunks
#define TOKW 32            // tokens per block
#define KSPLIT 8           // waves per block, each owns NCH/KSPLIT chunks
#define CHPS (NCH / KSPLIT)

typedef short bf16x8 __attribute__((ext_vector_type(8)));
typedef float f32x4  __attribute__((ext_vector_type(4)));

// RN split: x = hi + lo + f, |f| <= 2^-18 |x|. lo = x - hi is Sterbenz-exact.
__device__ __forceinline__ void split2(float f0, float f1, uint32_t& hw, uint32_t& lw) {
    float2 ff; ff.x = f0; ff.y = f1;
    __hip_bfloat162 h = __float22bfloat162_rn(ff);
    union { __hip_bfloat162 b; uint32_t u; } ch; ch.b = h;
    hw = ch.u;
    float h0 = __bfloat162float(h.x);
    float h1 = __bfloat162float(h.y);
    float2 gg; gg.x = f0 - h0; gg.y = f1 - h1;
    __hip_bfloat162 l = __float22bfloat162_rn(gg);
    union { __hip_bfloat162 b; uint32_t u; } cl; cl.b = l;
    lw = cl.u;
}

// ---------------- pre-pass: W fp32 -> RN bf16 hi/lo, fragment-ordered blob ----------------
// blob byte layout: c*16384 + ks*4096 + n4*1024 + lane*16 (hi; +8192 for lo)
// where lane = (e&15) | ((kgran&3)<<4), n4 = e>>4, ks = kgran>>2.
__global__ __launch_bounds__(512) void wsplit_kernel(const float* __restrict__ W,
                                                     char* __restrict__ blob) {
    const int c   = blockIdx.x;        // 0..63
    const int tid = threadIdx.x;       // 0..511
    const int e   = tid >> 3;          // expert 0..63
    const int g   = tid & 7;           // k-granule 0..7 (8 bf16 each)

    const float* src = W + (size_t)e * DM + c * BK + g * 8;
    float x[8];
    *(float4*)(x)     = *(const float4*)(src);
    *(float4*)(x + 4) = *(const float4*)(src + 4);

    uint32_t hiw[4], low[4];
#pragma unroll
    for (int j = 0; j < 4; ++j) split2(x[2 * j], x[2 * j + 1], hiw[j], low[j]);

    const int ks = g >> 2;
    const int ln = (e & 15) | ((g & 3) << 4);
    const int n4 = e >> 4;
    const size_t base = (size_t)c * 16384 + (size_t)ks * 4096 + (size_t)n4 * 1024 + (size_t)ln * 16;
    *(uint4*)(blob + base)        = *(uint4*)hiw;   // hi plane
    *(uint4*)(blob + base + 8192) = *(uint4*)low;   // lo plane
}

// ---------------- main kernel ----------------
// 512 threads = 8 waves. All waves share the block's 32 tokens; wave w owns
// K-chunks [w*CHPS, (w+1)*CHPS). No LDS / no barriers in the K-loop: A (=X)
// fragments are loaded per-lane straight from global and split in-register.
__global__ __launch_bounds__(512, 4) void router_mfma_kernel(
    const float* __restrict__ X,
    const char* __restrict__ blob,
    const float* __restrict__ Bv,
    float* __restrict__ out)
{
    __shared__ float part[KSPLIT][TOKW][NEXP];   // 64 KiB

    const int tid  = threadIdx.x;      // 0..511
    const int lane = tid & 63;
    const int wv   = tid >> 6;         // 0..7 = K-slice
    const long tok0 = (long)blockIdx.x * TOKW;

    const int tk = lane & 15;          // token-within-16 / expert col
    const int kg = lane >> 4;          // k-granule within 32-k subtile

    // per-lane A row bases (floats), at this wave's K-slice origin
    const float* a0 = X + (size_t)(tok0 + tk) * DM + (size_t)wv * (CHPS * BK) + kg * 8;
    const float* a1 = a0 + (size_t)16 * DM;

    f32x4 acc[2][4];
#pragma unroll
    for (int m = 0; m < 2; ++m)
#pragma unroll
        for (int n = 0; n < 4; ++n) acc[m][n] = (f32x4)0.0f;

#pragma unroll 1
    for (int ci = 0; ci < CHPS; ++ci) {
        const char* bb = blob + (size_t)(wv * CHPS + ci) * 16384;

        // ---- A: 8 floats per (m, ks), per-lane direct from global ----
        float ar[2][2][8];   // [m][ks][8]
#pragma unroll
        for (int m = 0; m < 2; ++m) {
            const float* am = (m == 0) ? a0 : a1;
#pragma unroll
            for (int ks = 0; ks < 2; ++ks) {
                const float* p = am + ci * BK + ks * 32;
                *(float4*)(ar[m][ks])     = *(const float4*)(p);
                *(float4*)(ar[m][ks] + 4) = *(const float4*)(p + 4);
            }
        }

        // split to fragments
        bf16x8 ah[2][2], al[2][2];   // [ks][m]
#pragma unroll
        for (int m = 0; m < 2; ++m)
#pragma unroll
            for (int ks = 0; ks < 2; ++ks) {
                uint32_t hw[4], lw[4];
#pragma unroll
                for (int j = 0; j < 4; ++j)
                    split2(ar[m][ks][2 * j], ar[m][ks][2 * j + 1], hw[j], lw[j]);
                ah[ks][m] = *(bf16x8*)hw;
                al[ks][m] = *(bf16x8*)lw;
            }

        // ---- B from L2 (fragment-ordered blob) + MFMA ----
#pragma unroll
        for (int ks = 0; ks < 2; ++ks) {
#pragma unroll
            for (int n = 0; n < 4; ++n) {
                const size_t bo = (size_t)ks * 4096 + (size_t)n * 1024 + (size_t)lane * 16;
                bf16x8 bh = *(const bf16x8*)(bb + bo);
                bf16x8 bl = *(const bf16x8*)(bb + 8192 + bo);
#pragma unroll
                for (int m = 0; m < 2; ++m) {
                    acc[m][n] = __builtin_amdgcn_mfma_f32_16x16x32_bf16(ah[ks][m], bh, acc[m][n], 0, 0, 0);
                    acc[m][n] = __builtin_amdgcn_mfma_f32_16x16x32_bf16(ah[ks][m], bl, acc[m][n], 0, 0, 0);
                    acc[m][n] = __builtin_amdgcn_mfma_f32_16x16x32_bf16(al[ks][m], bh, acc[m][n], 0, 0, 0);
                    acc[m][n] = __builtin_amdgcn_mfma_f32_16x16x32_bf16(al[ks][m], bl, acc[m][n], 0, 0, 0);
                }
            }
        }
    }

    // ---- write per-slice partial logits: token = m*16 + kg*4 + r, expert = n*16 + tk ----
#pragma unroll
    for (int m = 0; m < 2; ++m)
#pragma unroll
        for (int n = 0; n < 4; ++n)
#pragma unroll
            for (int r = 0; r < 4; ++r)
                part[wv][m * 16 + kg * 4 + r][n * 16 + tk] = acc[m][n][r];
    __syncthreads();

    // ---- reduce over K-slices: 2048 cells, 4 per thread ----
#pragma unroll
    for (int i = 0; i < 4; ++i) {
        const int cell = tid + i * 512;
        const int t = cell >> 6;
        const int e = cell & 63;
        float s = part[0][t][e];
#pragma unroll
        for (int w = 1; w < KSPLIT; ++w) s += part[w][t][e];
        part[0][t][e] = s;
    }
    __syncthreads();

    // ---- epilogue: bias + softmax + top-2 + dense scatter (lane = expert) ----
    const float bias = Bv[lane];
#pragma unroll 1
    for (int j = 0; j < TOKW / KSPLIT; ++j) {
        const int t = wv * (TOKW / KSPLIT) + j;
        float v = part[0][t][lane] + bias;

        float m1 = v;        int i1 = lane;
        float m2 = -3.4e38f; int i2 = 127;
#pragma unroll
        for (int s = 1; s < 64; s <<= 1) {
            float om1 = __shfl_xor(m1, s, 64);
            int   oi1 = __shfl_xor(i1, s, 64);
            float om2 = __shfl_xor(m2, s, 64);
            int   oi2 = __shfl_xor(i2, s, 64);
            bool bw = (om1 > m1) || (om1 == m1 && oi1 < i1);
            float l1v = bw ? m1 : om1;  int l1i = bw ? i1 : oi1;
            float w2v = bw ? om2 : m2;  int w2i = bw ? oi2 : i2;
            if (bw) { m1 = om1; i1 = oi1; }
            bool tw = (l1v > w2v) || (l1v == w2v && l1i < w2i);
            m2 = tw ? l1v : w2v;  i2 = tw ? l1i : w2i;
        }

        float p = expf(v - m1);
        float ssum = p;
#pragma unroll
        for (int s = 1; s < 64; s <<= 1) ssum += __shfl_xor(ssum, s, 64);

        float sc = (lane == i1 || lane == i2) ? (p / ssum) : 0.0f;
        out[(size_t)(tok0 + t) * NEXP + lane] = sc;
    }
}

extern "C" void kernel_launch(void* const* d_in, const int* in_sizes, int n_in,
                              void* d_out, int out_size, void* d_ws, size_t ws_size,
                              hipStream_t stream) {
    const float* X  = (const float*)d_in[0];   // [4,4096,4096] fp32
    const float* W  = (const float*)d_in[1];   // [64,4096] fp32
    const float* Bv = (const float*)d_in[2];   // [64] fp32
    float* out = (float*)d_out;                // [4,4096,64] fp32

    // W split blob: 64 chunks * 16 KiB = 1 MiB in d_ws
    char* blob = (char*)d_ws;
    wsplit_kernel<<<dim3(NCH), dim3(512), 0, stream>>>(W, blob);

    const int n_tokens = 4 * 4096;             // 16384
    router_mfma_kernel<<<dim3(n_tokens / TOKW), dim3(512), 0, stream>>>(X, blob, Bv, out);
}